// Round 15
// baseline (93.493 us; speedup 1.0000x reference)
//
#include <hip/hip_runtime.h>
#include <math.h>

#define NS 131072
#define DIM 256
#define NCH 16                 // chains (time-chunks) per block = MFMA N
#define OUTS 16                // output steps per chain
#define WARM 4                 // warmup steps (absmax bit-stable 0.25 for
                               // WARM in {128,64,24,12,8,6}; contraction
                               // ~0.036/step -> residual ~1.7e-6 after 4,
                               // vs bf16 state noise 4e-3)
#define NSTEPS (WARM + OUTS)   // 20 (even: epilogue parity unchanged)
#define OSTRIDE 260            // ostage row stride in floats

typedef short bf16x8 __attribute__((ext_vector_type(8)));
typedef short bf16x4 __attribute__((ext_vector_type(4)));
typedef float f32x4  __attribute__((ext_vector_type(4)));

__device__ __forceinline__ unsigned short f2bf(float x) {  // RTE f32->bf16
    unsigned u = __float_as_uint(x);
    return (unsigned short)((u + 0x7FFFu + ((u >> 16) & 1u)) >> 16);
}

// Parallel-in-time HMM forward via MFMA.
// 512 blocks (2/CU) x 16 chains; chain = 16 output steps + 4 warmup steps.
// Per block-step: S_new = ps_row ⊙ (256*T @ S), T as single RTE-bf16,
// fp32 accum in AGPRs, accumulation split into 2 chains of 4 MFMAs per
// output half (r15: halves the dependent-MFMA critical path).
//
// REGISTER-CLIFF WARNING (r7/r8): lives at the 128-reg cap of
// waves_per_eu(4,4). Extra long-lived f32x4 VGPR liveness in the step loop
// => scratch spills (WRITE_SIZE 135 -> 200..660 MB). Keep deferred output
// BEFORE the B-frag reads; keep the red[] path SCALAR.
//
// OUTPUT STREAMING (r11, +6%): normalized rows staged in LDS (parity
// double-buffer), streamed one step later as contiguous 1KB wave-stores.
// r12's 2KB bunching REGRESSED. STD WRITE BATCHING (r13): stds staged in
// LDS, single 1KB wave-store at epilogue.
__global__ void __launch_bounds__(512)
__attribute__((amdgpu_waves_per_eu(4, 4)))   // cap regs -> 4 waves/SIMD
hmm_mfma(const float* __restrict__ ps, const float* __restrict__ Tm,
         const float* __restrict__ state0, float* __restrict__ out) {
    __shared__ __align__(16) unsigned short Sbuf[2][4096];  // 2 x 8KB bf16 state
    __shared__ __align__(16) float red[2][8][NCH][4];       // [parity][wave][chain][{s,e1,e2,pad}]
    __shared__ __align__(16) float ostage[2][NCH][OSTRIDE]; // staged output rows
    __shared__ __align__(16) float sstd[NCH * OUTS];        // staged std (1KB)

    const int t    = threadIdx.x;
    const int lane = t & 63;
    const int wid  = t >> 6;      // wave 0..7 owns bins [32*wid, 32*wid+32)
    const int col  = lane & 15;   // chain index / MFMA n
    const int lq   = lane >> 4;   // k-group / C-row group
    const int blk  = blockIdx.x;
    const int binb = wid * 32;

    // ---- A-frags: T (x256) as single bf16, resident (16 frags = 64 regs) ----
    bf16x8 Ah[2][8];
    #pragma unroll
    for (int m = 0; m < 2; ++m) {
        const size_t row = (size_t)(binb + m * 16 + col);
        #pragma unroll
        for (int ks = 0; ks < 8; ++ks) {
            const float* p = Tm + row * DIM + ks * 32 + lq * 8;
            f32x4 u0 = *(const f32x4*)p;
            f32x4 u1 = *(const f32x4*)(p + 4);
            const float f[8] = {u0.x, u0.y, u0.z, u0.w, u1.x, u1.y, u1.z, u1.w};
            bf16x8 h;
            #pragma unroll
            for (int e = 0; e < 8; ++e) h[e] = (short)f2bf(f[e] * 256.0f);
            Ah[m][ks] = h;
        }
    }

    // ---- init buf0: all chains = uniform positive vector (scale-free) ----
    {
        bf16x8 one;
        #pragma unroll
        for (int e = 0; e < 8; ++e) one[e] = (short)0x3F80;
        *(bf16x8*)((char*)Sbuf + t * 16) = one;
    }
    __syncthreads();

    const int sbase = (blk * NCH + col) * OUTS - WARM;  // per-lane chain time base
    const int s0 = sbase < 0 ? 0 : sbase;
    f32x4 psc0 = *(const f32x4*)(ps + (size_t)s0 * DIM + binb + lq * 4);
    f32x4 psc1 = *(const f32x4*)(ps + (size_t)s0 * DIM + binb + 16 + lq * 4);

    const float bstep = 0.703125f;  // 180/256
    const float c0 = 30.0f + bstep * (float)(binb + lq * 4);

    f32x4 vh0 = {0.f, 0.f, 0.f, 0.f}, vh1 = {0.f, 0.f, 0.f, 0.f};

    for (int i = 0; i < NSTEPS; ++i) {
        const int cur = i & 1;

        if (i == WARM && blk == 0) {
            // re-seed chain 0 with the exact initial state (its warmup used
            // clamped ps[0] repeats).
            if (t < DIM) {
                const int k = t;
                char* p = (char*)Sbuf + cur * 8192 + (k >> 5) * 1024
                        + ((k >> 3) & 3) * 256 + (k & 7) * 2;
                *(unsigned short*)p = f2bf(state0[k]);
            }
            asm volatile("s_waitcnt lgkmcnt(0)" ::: "memory");
            __builtin_amdgcn_s_barrier();
            asm volatile("" ::: "memory");
        }

        // pin A-frags (forbid spill/remat)
        #pragma unroll
        for (int ks = 0; ks < 8; ++ks) {
            asm volatile("" : "+v"(Ah[0][ks]), "+v"(Ah[1][ks]));
        }

        // ---- (a) streamed store of step i-2's rows from ostage[i&1] ----
        // each wave stores 2 full rows as contiguous 1KB wave-stores
        if (i >= WARM + 2) {
            const int q  = i & 1;
            const int r0 = wid * 2;
            const int oi = i - 2 - WARM;
            const float* orow = &ostage[q][r0][0];
            const f32x4 a0 = *(const f32x4*)(orow + lane * 4);
            const f32x4 a1 = *(const f32x4*)(orow + OSTRIDE + lane * 4);
            const size_t gr = (size_t)(blk * NCH + r0) * OUTS + oi;
            *(f32x4*)(out + gr * DIM + lane * 4) = a0;
            *(f32x4*)(out + (gr + OUTS) * DIM + lane * 4) = a1;
        }

        // ---- (b) deferred normalize of step i-1 -> ostage[(i-1)&1] ----
        // (kept BEFORE the B-frag reads: minimizes peak register liveness)
        if (i > WARM) {
            const int pp = cur ^ 1;
            float sumv = 0.f;
            #pragma unroll
            for (int w = 0; w < 8; ++w) sumv += red[pp][w][col][0];
            const float inv = 1.0f / sumv;
            const f32x4 o0 = vh0 * inv, o1 = vh1 * inv;
            *(f32x4*)(&ostage[pp][col][binb + lq * 4]) = o0;
            *(f32x4*)(&ostage[pp][col][binb + 16 + lq * 4]) = o1;
            if (t < NCH) {  // col == t for these lanes; stage std in LDS
                float s1 = 0.f, s2 = 0.f;
                #pragma unroll
                for (int w = 0; w < 8; ++w) {
                    s1 += red[pp][w][t][1];
                    s2 += red[pp][w][t][2];
                }
                const float m1 = s1 * inv, m2 = s2 * inv;
                const float var = m2 - m1 * m1;
                sstd[t * OUTS + (i - 1 - WARM)] = sqrtf(var > 0.f ? var : 0.f);
            }
        }

        // ---- B-frags: 8 stride-1 ds_read_b128 (conflict-free) ----
        const char* sbp = (const char*)Sbuf + cur * 8192;
        bf16x8 Bf[8];
        #pragma unroll
        for (int ks = 0; ks < 8; ++ks)
            Bf[ks] = *(const bf16x8*)(sbp + ks * 1024 + lane * 16);

        // prefetch next step's ps row segment (clamped)
        int snx = sbase + i + 1;
        snx = snx < 0 ? 0 : (snx > NS - 1 ? NS - 1 : snx);
        f32x4 pn0 = *(const f32x4*)(ps + (size_t)snx * DIM + binb + lq * 4);
        f32x4 pn1 = *(const f32x4*)(ps + (size_t)snx * DIM + binb + 16 + lq * 4);

        // ---- 16 MFMA: acc = T_bf16 @ S, fp32 accum.
        //      4 independent chains of 4 (r15: halves dep-chain latency) ----
        f32x4 acc0a = {0.f, 0.f, 0.f, 0.f}, acc0b = {0.f, 0.f, 0.f, 0.f};
        f32x4 acc1a = {0.f, 0.f, 0.f, 0.f}, acc1b = {0.f, 0.f, 0.f, 0.f};
        #pragma unroll
        for (int ks = 0; ks < 4; ++ks) {
            acc0a = __builtin_amdgcn_mfma_f32_16x16x32_bf16(Ah[0][ks], Bf[ks], acc0a, 0, 0, 0);
            acc1a = __builtin_amdgcn_mfma_f32_16x16x32_bf16(Ah[1][ks], Bf[ks], acc1a, 0, 0, 0);
            acc0b = __builtin_amdgcn_mfma_f32_16x16x32_bf16(Ah[0][ks + 4], Bf[ks + 4], acc0b, 0, 0, 0);
            acc1b = __builtin_amdgcn_mfma_f32_16x16x32_bf16(Ah[1][ks + 4], Bf[ks + 4], acc1b, 0, 0, 0);
        }
        const f32x4 acc0 = acc0a + acc0b;
        const f32x4 acc1 = acc1a + acc1b;

        const f32x4 v0 = acc0 * psc0;  // bins binb+lq*4+{0..3}, chain col
        const f32x4 v1 = acc1 * psc1;  // bins binb+16+lq*4+{0..3}

        // ---- next-state bf16 write: 2 contiguous ds_write_b64 ----
        {
            char* db = (char*)Sbuf + (cur ^ 1) * 8192 + wid * 1024
                     + (lq >> 1) * 256 + col * 16 + ((4 * lq) & 7) * 2;
            bf16x4 w0, w1;
            w0[0] = (short)f2bf(v0.x); w0[1] = (short)f2bf(v0.y);
            w0[2] = (short)f2bf(v0.z); w0[3] = (short)f2bf(v0.w);
            w1[0] = (short)f2bf(v1.x); w1[1] = (short)f2bf(v1.y);
            w1[2] = (short)f2bf(v1.z); w1[3] = (short)f2bf(v1.w);
            *(bf16x4*)db = w0;
            *(bf16x4*)(db + 512) = w1;  // bins +16 -> lq' += 2
        }

        // ---- moment partials (output steps), same-barrier reduction ----
        if (i >= WARM) {
            float sp = 0.f, e1 = 0.f, e2 = 0.f;
            {
                const float fv[4] = {v0.x, v0.y, v0.z, v0.w};
                #pragma unroll
                for (int j = 0; j < 4; ++j) {
                    const float b = c0 + bstep * (float)j;
                    sp += fv[j];
                    const float tb = fv[j] * b;
                    e1 += tb; e2 += tb * b;
                }
            }
            {
                const float fv[4] = {v1.x, v1.y, v1.z, v1.w};
                #pragma unroll
                for (int j = 0; j < 4; ++j) {
                    const float b = c0 + 11.25f + bstep * (float)j;
                    sp += fv[j];
                    const float tb = fv[j] * b;
                    e1 += tb; e2 += tb * b;
                }
            }
            // reduce over the 4 lq-lanes of this chain (lanes col+16k)
            sp += __shfl_xor(sp, 16); sp += __shfl_xor(sp, 32);
            e1 += __shfl_xor(e1, 16); e1 += __shfl_xor(e1, 32);
            e2 += __shfl_xor(e2, 16); e2 += __shfl_xor(e2, 32);
            if (lane < 16) {
                red[cur][wid][lane][0] = sp;
                red[cur][wid][lane][1] = e1;
                red[cur][wid][lane][2] = e2;
            }
            vh0 = v0; vh1 = v1;
        }

        // single per-step barrier (orders state + red + ostage writes)
        asm volatile("s_waitcnt lgkmcnt(0)" ::: "memory");
        __builtin_amdgcn_s_barrier();
        asm volatile("" ::: "memory");

        psc0 = pn0; psc1 = pn1;
    }

    // ---- epilogue A: stream rows oi = OUTS-2 (staged at step NSTEPS-1) ----
    {
        const int q  = NSTEPS & 1;   // == (NSTEPS-2)&1
        const int r0 = wid * 2;
        const float* orow = &ostage[q][r0][0];
        const f32x4 a0 = *(const f32x4*)(orow + lane * 4);
        const f32x4 a1 = *(const f32x4*)(orow + OSTRIDE + lane * 4);
        const size_t gr = (size_t)(blk * NCH + r0) * OUTS + (OUTS - 2);
        *(f32x4*)(out + gr * DIM + lane * 4) = a0;
        *(f32x4*)(out + (gr + OUTS) * DIM + lane * 4) = a1;
    }

    // ---- epilogue B: normalize final row (oi=OUTS-1) into the now-free
    //      ostage buffer; stage its std ----
    {
        const int pp = (NSTEPS - 1) & 1;
        const int qf = pp;           // ostage[pp] fully streamed at i=NSTEPS-1
        float sumv = 0.f;
        #pragma unroll
        for (int w = 0; w < 8; ++w) sumv += red[pp][w][col][0];
        const float inv = 1.0f / sumv;
        const f32x4 o0 = vh0 * inv, o1 = vh1 * inv;
        *(f32x4*)(&ostage[qf][col][binb + lq * 4]) = o0;
        *(f32x4*)(&ostage[qf][col][binb + 16 + lq * 4]) = o1;
        if (t < NCH) {
            float s1 = 0.f, s2 = 0.f;
            #pragma unroll
            for (int w = 0; w < 8; ++w) {
                s1 += red[pp][w][t][1];
                s2 += red[pp][w][t][2];
            }
            const float m1 = s1 * inv, m2 = s2 * inv;
            const float var = m2 - m1 * m1;
            sstd[t * OUTS + (OUTS - 1)] = sqrtf(var > 0.f ? var : 0.f);
        }
    }
    __syncthreads();

    // ---- epilogue C: stream final rows (oi=OUTS-1) + the 1KB std block ----
    {
        const int qf = (NSTEPS - 1) & 1;
        const int r0 = wid * 2;
        const float* orow = &ostage[qf][r0][0];
        const f32x4 a0 = *(const f32x4*)(orow + lane * 4);
        const f32x4 a1 = *(const f32x4*)(orow + OSTRIDE + lane * 4);
        const size_t gr = (size_t)(blk * NCH + r0) * OUTS + (OUTS - 1);
        *(f32x4*)(out + gr * DIM + lane * 4) = a0;
        *(f32x4*)(out + (gr + OUTS) * DIM + lane * 4) = a1;
        if (wid == 0) {  // 256 stds = contiguous 1KB at out[NS*DIM + blk*256]
            const f32x4 sv = *(const f32x4*)(&sstd[lane * 4]);
            *(f32x4*)(out + (size_t)NS * DIM + blk * (NCH * OUTS) + lane * 4) = sv;
        }
    }
}

extern "C" void kernel_launch(void* const* d_in, const int* in_sizes, int n_in,
                              void* d_out, int out_size, void* d_ws, size_t ws_size,
                              hipStream_t stream) {
    const float* ps     = (const float*)d_in[0];
    const float* Tm     = (const float*)d_in[1];
    const float* state0 = (const float*)d_in[2];
    float* out = (float*)d_out;

    hmm_mfma<<<dim3(NS / (NCH * OUTS)), dim3(512), 0, stream>>>(ps, Tm, state0, out);
}

// Round 16
// 73.798 us; speedup vs baseline: 1.2669x; 1.2669x over previous
//
#include <hip/hip_runtime.h>
#include <math.h>

#define NS 131072
#define DIM 256
#define NCH 16                 // chains (time-chunks) per block = MFMA N
#define OUTS 16                // output steps per chain
#define WARM 4                 // warmup steps (absmax bit-stable 0.25 for
                               // WARM in {128,64,24,12,8,6,4}; contraction
                               // ~0.036/step -> residual ~1.7e-6 after 4,
                               // vs bf16 state noise 4e-3)
#define NSTEPS (WARM + OUTS)   // 20 (even: epilogue parity unchanged)
#define OSTRIDE 260            // ostage row stride in floats

typedef short bf16x8 __attribute__((ext_vector_type(8)));
typedef short bf16x4 __attribute__((ext_vector_type(4)));
typedef float f32x4  __attribute__((ext_vector_type(4)));

__device__ __forceinline__ unsigned short f2bf(float x) {  // RTE f32->bf16
    unsigned u = __float_as_uint(x);
    return (unsigned short)((u + 0x7FFFu + ((u >> 16) & 1u)) >> 16);
}

// Parallel-in-time HMM forward via MFMA.
// 512 blocks (2/CU) x 16 chains; chain = 16 output steps + 4 warmup steps.
// Per block-step: S_new = ps_row ⊙ (256*T @ S), T as single RTE-bf16,
// fp32 accum in AGPRs (single 8-deep chain per output half -- r15's 2x4
// split REGRESSED: gfx950's UNIFIED VGPR/AGPR file means +8 accum regs
// tipped the register cliff, WRITE 134.7->143.9 MB spills).
//
// REGISTER-CLIFF WARNING (r7/r8/r15): lives at the 128-reg cap of
// waves_per_eu(4,4). ANY extra ~8-reg liveness in the step loop (VGPR or
// AGPR -- unified file!) => scratch spills (WRITE_SIZE 135 -> 144..660 MB)
// and 20-200% slowdown. Keep deferred output BEFORE the B-frag reads;
// keep the red[] path SCALAR; keep the MFMA chain single.
//
// OUTPUT STREAMING (r11, +6%): normalized rows staged in LDS (parity
// double-buffer), streamed one step later as contiguous 1KB wave-stores.
// r12's 2KB bunching REGRESSED. STD WRITE BATCHING (r13): stds staged in
// LDS, single 1KB wave-store at epilogue.
__global__ void __launch_bounds__(512)
__attribute__((amdgpu_waves_per_eu(4, 4)))   // cap regs -> 4 waves/SIMD
hmm_mfma(const float* __restrict__ ps, const float* __restrict__ Tm,
         const float* __restrict__ state0, float* __restrict__ out) {
    __shared__ __align__(16) unsigned short Sbuf[2][4096];  // 2 x 8KB bf16 state
    __shared__ __align__(16) float red[2][8][NCH][4];       // [parity][wave][chain][{s,e1,e2,pad}]
    __shared__ __align__(16) float ostage[2][NCH][OSTRIDE]; // staged output rows
    __shared__ __align__(16) float sstd[NCH * OUTS];        // staged std (1KB)

    const int t    = threadIdx.x;
    const int lane = t & 63;
    const int wid  = t >> 6;      // wave 0..7 owns bins [32*wid, 32*wid+32)
    const int col  = lane & 15;   // chain index / MFMA n
    const int lq   = lane >> 4;   // k-group / C-row group
    const int blk  = blockIdx.x;
    const int binb = wid * 32;

    // ---- A-frags: T (x256) as single bf16, resident (16 frags = 64 regs) ----
    bf16x8 Ah[2][8];
    #pragma unroll
    for (int m = 0; m < 2; ++m) {
        const size_t row = (size_t)(binb + m * 16 + col);
        #pragma unroll
        for (int ks = 0; ks < 8; ++ks) {
            const float* p = Tm + row * DIM + ks * 32 + lq * 8;
            f32x4 u0 = *(const f32x4*)p;
            f32x4 u1 = *(const f32x4*)(p + 4);
            const float f[8] = {u0.x, u0.y, u0.z, u0.w, u1.x, u1.y, u1.z, u1.w};
            bf16x8 h;
            #pragma unroll
            for (int e = 0; e < 8; ++e) h[e] = (short)f2bf(f[e] * 256.0f);
            Ah[m][ks] = h;
        }
    }

    // ---- init buf0: all chains = uniform positive vector (scale-free) ----
    {
        bf16x8 one;
        #pragma unroll
        for (int e = 0; e < 8; ++e) one[e] = (short)0x3F80;
        *(bf16x8*)((char*)Sbuf + t * 16) = one;
    }
    __syncthreads();

    const int sbase = (blk * NCH + col) * OUTS - WARM;  // per-lane chain time base
    const int s0 = sbase < 0 ? 0 : sbase;
    f32x4 psc0 = *(const f32x4*)(ps + (size_t)s0 * DIM + binb + lq * 4);
    f32x4 psc1 = *(const f32x4*)(ps + (size_t)s0 * DIM + binb + 16 + lq * 4);

    const float bstep = 0.703125f;  // 180/256
    const float c0 = 30.0f + bstep * (float)(binb + lq * 4);

    f32x4 vh0 = {0.f, 0.f, 0.f, 0.f}, vh1 = {0.f, 0.f, 0.f, 0.f};

    for (int i = 0; i < NSTEPS; ++i) {
        const int cur = i & 1;

        if (i == WARM && blk == 0) {
            // re-seed chain 0 with the exact initial state (its warmup used
            // clamped ps[0] repeats).
            if (t < DIM) {
                const int k = t;
                char* p = (char*)Sbuf + cur * 8192 + (k >> 5) * 1024
                        + ((k >> 3) & 3) * 256 + (k & 7) * 2;
                *(unsigned short*)p = f2bf(state0[k]);
            }
            asm volatile("s_waitcnt lgkmcnt(0)" ::: "memory");
            __builtin_amdgcn_s_barrier();
            asm volatile("" ::: "memory");
        }

        // pin A-frags (forbid spill/remat)
        #pragma unroll
        for (int ks = 0; ks < 8; ++ks) {
            asm volatile("" : "+v"(Ah[0][ks]), "+v"(Ah[1][ks]));
        }

        // ---- (a) streamed store of step i-2's rows from ostage[i&1] ----
        // each wave stores 2 full rows as contiguous 1KB wave-stores
        if (i >= WARM + 2) {
            const int q  = i & 1;
            const int r0 = wid * 2;
            const int oi = i - 2 - WARM;
            const float* orow = &ostage[q][r0][0];
            const f32x4 a0 = *(const f32x4*)(orow + lane * 4);
            const f32x4 a1 = *(const f32x4*)(orow + OSTRIDE + lane * 4);
            const size_t gr = (size_t)(blk * NCH + r0) * OUTS + oi;
            *(f32x4*)(out + gr * DIM + lane * 4) = a0;
            *(f32x4*)(out + (gr + OUTS) * DIM + lane * 4) = a1;
        }

        // ---- (b) deferred normalize of step i-1 -> ostage[(i-1)&1] ----
        // (kept BEFORE the B-frag reads: minimizes peak register liveness)
        if (i > WARM) {
            const int pp = cur ^ 1;
            float sumv = 0.f;
            #pragma unroll
            for (int w = 0; w < 8; ++w) sumv += red[pp][w][col][0];
            const float inv = 1.0f / sumv;
            const f32x4 o0 = vh0 * inv, o1 = vh1 * inv;
            *(f32x4*)(&ostage[pp][col][binb + lq * 4]) = o0;
            *(f32x4*)(&ostage[pp][col][binb + 16 + lq * 4]) = o1;
            if (t < NCH) {  // col == t for these lanes; stage std in LDS
                float s1 = 0.f, s2 = 0.f;
                #pragma unroll
                for (int w = 0; w < 8; ++w) {
                    s1 += red[pp][w][t][1];
                    s2 += red[pp][w][t][2];
                }
                const float m1 = s1 * inv, m2 = s2 * inv;
                const float var = m2 - m1 * m1;
                sstd[t * OUTS + (i - 1 - WARM)] = sqrtf(var > 0.f ? var : 0.f);
            }
        }

        // ---- B-frags: 8 stride-1 ds_read_b128 (conflict-free) ----
        const char* sbp = (const char*)Sbuf + cur * 8192;
        bf16x8 Bf[8];
        #pragma unroll
        for (int ks = 0; ks < 8; ++ks)
            Bf[ks] = *(const bf16x8*)(sbp + ks * 1024 + lane * 16);

        // prefetch next step's ps row segment (clamped)
        int snx = sbase + i + 1;
        snx = snx < 0 ? 0 : (snx > NS - 1 ? NS - 1 : snx);
        f32x4 pn0 = *(const f32x4*)(ps + (size_t)snx * DIM + binb + lq * 4);
        f32x4 pn1 = *(const f32x4*)(ps + (size_t)snx * DIM + binb + 16 + lq * 4);

        // ---- 16 MFMA: acc = T_bf16 @ S, fp32 accum ----
        f32x4 acc0 = {0.f, 0.f, 0.f, 0.f};
        f32x4 acc1 = {0.f, 0.f, 0.f, 0.f};
        #pragma unroll
        for (int ks = 0; ks < 8; ++ks) {
            acc0 = __builtin_amdgcn_mfma_f32_16x16x32_bf16(Ah[0][ks], Bf[ks], acc0, 0, 0, 0);
            acc1 = __builtin_amdgcn_mfma_f32_16x16x32_bf16(Ah[1][ks], Bf[ks], acc1, 0, 0, 0);
        }

        const f32x4 v0 = acc0 * psc0;  // bins binb+lq*4+{0..3}, chain col
        const f32x4 v1 = acc1 * psc1;  // bins binb+16+lq*4+{0..3}

        // ---- next-state bf16 write: 2 contiguous ds_write_b64 ----
        {
            char* db = (char*)Sbuf + (cur ^ 1) * 8192 + wid * 1024
                     + (lq >> 1) * 256 + col * 16 + ((4 * lq) & 7) * 2;
            bf16x4 w0, w1;
            w0[0] = (short)f2bf(v0.x); w0[1] = (short)f2bf(v0.y);
            w0[2] = (short)f2bf(v0.z); w0[3] = (short)f2bf(v0.w);
            w1[0] = (short)f2bf(v1.x); w1[1] = (short)f2bf(v1.y);
            w1[2] = (short)f2bf(v1.z); w1[3] = (short)f2bf(v1.w);
            *(bf16x4*)db = w0;
            *(bf16x4*)(db + 512) = w1;  // bins +16 -> lq' += 2
        }

        // ---- moment partials (output steps), same-barrier reduction ----
        if (i >= WARM) {
            float sp = 0.f, e1 = 0.f, e2 = 0.f;
            {
                const float fv[4] = {v0.x, v0.y, v0.z, v0.w};
                #pragma unroll
                for (int j = 0; j < 4; ++j) {
                    const float b = c0 + bstep * (float)j;
                    sp += fv[j];
                    const float tb = fv[j] * b;
                    e1 += tb; e2 += tb * b;
                }
            }
            {
                const float fv[4] = {v1.x, v1.y, v1.z, v1.w};
                #pragma unroll
                for (int j = 0; j < 4; ++j) {
                    const float b = c0 + 11.25f + bstep * (float)j;
                    sp += fv[j];
                    const float tb = fv[j] * b;
                    e1 += tb; e2 += tb * b;
                }
            }
            // reduce over the 4 lq-lanes of this chain (lanes col+16k)
            sp += __shfl_xor(sp, 16); sp += __shfl_xor(sp, 32);
            e1 += __shfl_xor(e1, 16); e1 += __shfl_xor(e1, 32);
            e2 += __shfl_xor(e2, 16); e2 += __shfl_xor(e2, 32);
            if (lane < 16) {
                red[cur][wid][lane][0] = sp;
                red[cur][wid][lane][1] = e1;
                red[cur][wid][lane][2] = e2;
            }
            vh0 = v0; vh1 = v1;
        }

        // single per-step barrier (orders state + red + ostage writes)
        asm volatile("s_waitcnt lgkmcnt(0)" ::: "memory");
        __builtin_amdgcn_s_barrier();
        asm volatile("" ::: "memory");

        psc0 = pn0; psc1 = pn1;
    }

    // ---- epilogue A: stream rows oi = OUTS-2 (staged at step NSTEPS-1) ----
    {
        const int q  = NSTEPS & 1;   // == (NSTEPS-2)&1
        const int r0 = wid * 2;
        const float* orow = &ostage[q][r0][0];
        const f32x4 a0 = *(const f32x4*)(orow + lane * 4);
        const f32x4 a1 = *(const f32x4*)(orow + OSTRIDE + lane * 4);
        const size_t gr = (size_t)(blk * NCH + r0) * OUTS + (OUTS - 2);
        *(f32x4*)(out + gr * DIM + lane * 4) = a0;
        *(f32x4*)(out + (gr + OUTS) * DIM + lane * 4) = a1;
    }

    // ---- epilogue B: normalize final row (oi=OUTS-1) into the now-free
    //      ostage buffer; stage its std ----
    {
        const int pp = (NSTEPS - 1) & 1;
        const int qf = pp;           // ostage[pp] fully streamed at i=NSTEPS-1
        float sumv = 0.f;
        #pragma unroll
        for (int w = 0; w < 8; ++w) sumv += red[pp][w][col][0];
        const float inv = 1.0f / sumv;
        const f32x4 o0 = vh0 * inv, o1 = vh1 * inv;
        *(f32x4*)(&ostage[qf][col][binb + lq * 4]) = o0;
        *(f32x4*)(&ostage[qf][col][binb + 16 + lq * 4]) = o1;
        if (t < NCH) {
            float s1 = 0.f, s2 = 0.f;
            #pragma unroll
            for (int w = 0; w < 8; ++w) {
                s1 += red[pp][w][t][1];
                s2 += red[pp][w][t][2];
            }
            const float m1 = s1 * inv, m2 = s2 * inv;
            const float var = m2 - m1 * m1;
            sstd[t * OUTS + (OUTS - 1)] = sqrtf(var > 0.f ? var : 0.f);
        }
    }
    __syncthreads();

    // ---- epilogue C: stream final rows (oi=OUTS-1) + the 1KB std block ----
    {
        const int qf = (NSTEPS - 1) & 1;
        const int r0 = wid * 2;
        const float* orow = &ostage[qf][r0][0];
        const f32x4 a0 = *(const f32x4*)(orow + lane * 4);
        const f32x4 a1 = *(const f32x4*)(orow + OSTRIDE + lane * 4);
        const size_t gr = (size_t)(blk * NCH + r0) * OUTS + (OUTS - 1);
        *(f32x4*)(out + gr * DIM + lane * 4) = a0;
        *(f32x4*)(out + (gr + OUTS) * DIM + lane * 4) = a1;
        if (wid == 0) {  // 256 stds = contiguous 1KB at out[NS*DIM + blk*256]
            const f32x4 sv = *(const f32x4*)(&sstd[lane * 4]);
            *(f32x4*)(out + (size_t)NS * DIM + blk * (NCH * OUTS) + lane * 4) = sv;
        }
    }
}

extern "C" void kernel_launch(void* const* d_in, const int* in_sizes, int n_in,
                              void* d_out, int out_size, void* d_ws, size_t ws_size,
                              hipStream_t stream) {
    const float* ps     = (const float*)d_in[0];
    const float* Tm     = (const float*)d_in[1];
    const float* state0 = (const float*)d_in[2];
    float* out = (float*)d_out;

    hmm_mfma<<<dim3(NS / (NCH * OUTS)), dim3(512), 0, stream>>>(ps, Tm, state0, out);
}